// Round 9
// baseline (506.727 us; speedup 1.0000x reference)
//
#include <hip/hip_runtime.h>
#include <hip/hip_cooperative_groups.h>
#include <math.h>

namespace cg = cooperative_groups;

#define C_HUB 1.345f

// ---------------- DPP helpers (VALU-pipe cross-lane) ----
template<int CTRL, bool BC>
__device__ __forceinline__ float fdpp(float old_, float src) {
    return __int_as_float(__builtin_amdgcn_update_dpp(
        __float_as_int(old_), __float_as_int(src), CTRL, 0xf, 0xf, BC));
}
// wave64 sum; result valid at lane 63 only
__device__ __forceinline__ float wsum63(float v) {
    v += fdpp<0x111, true>(0.f, v);   // row_shr:1
    v += fdpp<0x112, true>(0.f, v);   // row_shr:2
    v += fdpp<0x114, true>(0.f, v);   // row_shr:4
    v += fdpp<0x118, true>(0.f, v);   // row_shr:8
    v += fdpp<0x142, true>(0.f, v);   // row_bcast:15
    v += fdpp<0x143, true>(0.f, v);   // row_bcast:31
    return v;
}
template<int CTRL>
__device__ __forceinline__ unsigned udpp_keep(unsigned v) {
    return (unsigned)__builtin_amdgcn_update_dpp((int)v, (int)v, CTRL, 0xf, 0xf, false);
}
__device__ __forceinline__ unsigned wmin63(unsigned v) {
    v = min(v, udpp_keep<0x111>(v));
    v = min(v, udpp_keep<0x112>(v));
    v = min(v, udpp_keep<0x114>(v));
    v = min(v, udpp_keep<0x118>(v));
    v = min(v, udpp_keep<0x142>(v));
    v = min(v, udpp_keep<0x143>(v));
    return v;
}
__device__ __forceinline__ float bcast63(float v) {
    return __int_as_float(__builtin_amdgcn_readlane(__float_as_int(v), 63));
}

// monotone f32 <-> u32 key maps
__device__ __forceinline__ unsigned f2k(float f) {
    unsigned b = __float_as_uint(f);
    return (b & 0x80000000u) ? ~b : (b | 0x80000000u);
}
__device__ __forceinline__ float k2f(unsigned k) {
    return __uint_as_float((k & 0x80000000u) ? (k ^ 0x80000000u) : ~k);
}

// n-th smallest (1-indexed) of 1024 keys (16/lane), wave-synchronous
__device__ __forceinline__ unsigned wave_sel(const unsigned k[16], int n) {
    unsigned hi = 0u;
    for (int b = 31; b >= 0; --b) {
        unsigned pat = hi >> b;
        int cnt = 0;
        #pragma unroll
        for (int v = 0; v < 16; ++v)
            cnt += __popcll(__ballot((k[v] >> b) == pat));
        if (n > cnt) { hi |= (1u << b); n -= cnt; }
    }
    return hi;
}
// exact median (mean of middle two) of the 1024 keys
__device__ __forceinline__ float wave_median(const unsigned k[16]) {
    unsigned k1 = wave_sel(k, 512);
    int cle = 0;
    #pragma unroll
    for (int v = 0; v < 16; ++v) cle += __popcll(__ballot(k[v] <= k1));
    unsigned k2 = k1;
    if (cle < 513) {
        unsigned mg = 0xFFFFFFFFu;
        #pragma unroll
        for (int v = 0; v < 16; ++v) if (k[v] > k1) mg = min(mg, k[v]);
        mg = wmin63(mg);
        k2 = (unsigned)__builtin_amdgcn_readlane((int)mg, 63);
    }
    return 0.5f * (k2f(k1) + k2f(k2));
}

// ---------------- shared memory layout ----------------
struct SmAll {
    float rp[2][1024];
    float beta[32][2];
    float g[32][35];      // g[e][1+c] = Ginv[e][c]; cols 0,33 zero guards
    float z[2][3][32];
    float kern[2][9];
    float part[4][2];
    float scale[2];
};                        // 3452 floats
#define SM_FLOATS 3456    // 13824 B

// ---------------------------------------------------------------------------
// Transpose two 32x32 X-tiles (tiles 2b, 2b+1)
// ---------------------------------------------------------------------------
__device__ __forceinline__ void transpose2(float* sm, const float* __restrict__ X,
                                           float* __restrict__ XT, int b) {
    const int tid = threadIdx.x;
    const int tx = tid & 31, ty = tid >> 5;     // 32 x 8
    #pragma unroll 1
    for (int s = 0; s < 2; ++s) {
        const int tile = (b << 1) + s;
        const int bx = tile & 31, by = tile >> 5;
        __syncthreads();
        for (int dy = ty; dy < 32; dy += 8)
            sm[dy * 33 + tx] = X[(by * 32 + dy) * 1024 + bx * 32 + tx];
        __syncthreads();
        for (int dy = ty; dy < 32; dy += 8)
            XT[(bx * 32 + dy) * 1024 + by * 32 + tx] = sm[tx * 33 + dy];
    }
}

__device__ __forceinline__ void ut_col(const float* __restrict__ U,
                                       float* __restrict__ UT, int col) {
    for (int m = threadIdx.x; m < 1024; m += 256)
        UT[(col << 10) + m] = U[m * 32 + col];
}

// ---------------------------------------------------------------------------
// Partial Gram of U (1024x32 row-major), rows 32b..32b+31:
//   Gpart[b][c1*32+c2] = sum_k U[32b+k][c1]*U[32b+k][c2]
// ---------------------------------------------------------------------------
__device__ __forceinline__ void gramU_partial(float* sm, const float* __restrict__ U,
                                              float* __restrict__ Gpart, int b) {
    const int tid = threadIdx.x;
    __syncthreads();
    #pragma unroll
    for (int s = 0; s < 4; ++s) {
        int e = tid + (s << 8);
        int k = e >> 5, c = e & 31;
        sm[k * 33 + c] = U[((b << 5) + k) * 32 + c];
    }
    __syncthreads();
    #pragma unroll
    for (int s = 0; s < 4; ++s) {
        int e = tid + (s << 8);
        int c1 = e >> 5, c2 = e & 31;
        float a = 0.f;
        #pragma unroll 8
        for (int k = 0; k < 32; ++k)
            a += sm[k * 33 + c1] * sm[k * 33 + c2];
        Gpart[(b << 10) + e] = a;
    }
}

// ---------------------------------------------------------------------------
// Partial Gram of Vn (32x1024 row-major), cols 32b..32b+31:
//   Gpart[b][c1*32+c2] = sum_i Vn[c1][32b+i]*Vn[c2][32b+i]
// ---------------------------------------------------------------------------
__device__ __forceinline__ void gramVn_partial(float* sm, const float* __restrict__ Vn,
                                               float* __restrict__ Gpart, int b) {
    const int tid = threadIdx.x;
    __syncthreads();
    #pragma unroll
    for (int s = 0; s < 4; ++s) {
        int e = tid + (s << 8);
        int c = e >> 5, i = e & 31;
        sm[c * 33 + i] = Vn[(c << 10) + (b << 5) + i];
    }
    __syncthreads();
    #pragma unroll
    for (int s = 0; s < 4; ++s) {
        int e = tid + (s << 8);
        int c1 = e >> 5, c2 = e & 31;
        float a = 0.f;
        #pragma unroll 8
        for (int i = 0; i < 32; ++i)
            a += sm[c1 * 33 + i] * sm[c2 * 33 + i];
        Gpart[(b << 10) + e] = a;
    }
}

// ---------------------------------------------------------------------------
// One-wave register Gauss-Jordan of the 32x32 SPD matrix staged in sm[0..1023]
// ---------------------------------------------------------------------------
__device__ __forceinline__ void gj_inv_from_sm(const float* sm, float* __restrict__ Ginv) {
    const int tid = threadIdx.x;
    if (tid < 64) {
        float col[32];
        if (tid < 32) {
            #pragma unroll
            for (int r = 0; r < 32; ++r) col[r] = sm[(r << 5) + tid];
        } else {
            #pragma unroll
            for (int r = 0; r < 32; ++r) col[r] = (tid - 32 == r) ? 1.f : 0.f;
        }
        #pragma unroll
        for (int k = 0; k < 32; ++k) {
            float piv = __shfl(col[k], k, 64);
            float pr = 1.0f / piv;
            col[k] *= pr;
            #pragma unroll
            for (int r = 0; r < 32; ++r) {
                if (r == k) continue;
                float f = __shfl(col[r], k, 64);
                col[r] -= f * col[k];
            }
        }
        if (tid >= 32) {
            #pragma unroll
            for (int r = 0; r < 32; ++r) Ginv[(r << 5) + (tid - 32)] = col[r];
        }
    }
}

// ---------------------------------------------------------------------------
// Reduce 32 Gram partials then invert (single block)
// ---------------------------------------------------------------------------
__device__ __forceinline__ void reduce_inv(float* sm, const float* __restrict__ Gpart,
                                           float* __restrict__ Ginv) {
    const int tid = threadIdx.x;
    __syncthreads();
    #pragma unroll
    for (int s = 0; s < 4; ++s) {
        int e = tid + (s << 8);
        float a = 0.f;
        #pragma unroll 8
        for (int p = 0; p < 32; ++p) a += Gpart[(p << 10) + e];
        sm[e] = a;
    }
    __syncthreads();
    gj_inv_from_sm(sm, Ginv);
}

// ---------------------------------------------------------------------------
// IRLS, 2 tasks (j = 2*b2, 2*b2+1), 256 threads — R6 body (proven, 69 us).
// unroll 8 (matvec) / unroll 2 (z kk-loop) cap in-flight loads (R5 spill fix).
// ---------------------------------------------------------------------------
__device__ __forceinline__ void irls2_block(
    float* smraw, int b2, const float* __restrict__ Yr, const float* __restrict__ A32,
    const float* __restrict__ GinvG, const float* __restrict__ kb,
    const float* __restrict__ bsrc, float* __restrict__ vnew,
    float* __restrict__ out, int phase)
{
    SmAll& S = *reinterpret_cast<SmAll*>(smraw);
    const int tid = threadIdx.x;
    const int lane = tid & 63, wv_id = tid >> 6;
    const float4* Y4 = (const float4*)Yr;
    const float4* A4 = (const float4*)A32;

    __syncthreads();   // guard vs. prior phase's sm use
    for (int i = tid; i < 1024; i += 256) {
        int e = i >> 5, c = i & 31;
        S.g[e][1 + c] = GinvG[i];
    }
    if (tid < 32) S.g[tid][0] = 0.f;
    else if (tid < 64) S.g[tid - 32][33] = 0.f;
    if (tid >= 64 && tid < 128) {
        int e = tid - 64, t = e >> 5, c = e & 31, j = (b2 << 1) + t;
        S.beta[c][t] = (phase == 0) ? bsrc[(c << 10) + j] : bsrc[j * 32 + c];
    }
    if (tid >= 192 && tid < 210) {
        int e = tid - 192, t = e / 9, r = e % 9, j = (b2 << 1) + t;
        S.kern[t][r] = (phase == 0) ? kb[j * 9 + r] : kb[j * 9 + (r % 3) * 3 + (r / 3)];
    }
    __syncthreads();

    auto matvec = [&](float4* r) {
        r[0] = Y4[(((b2 << 1) + 0) << 8) + tid];
        r[1] = Y4[(((b2 << 1) + 1) << 8) + tid];
        #pragma unroll 8
        for (int c = 0; c < 32; ++c) {
            float2 bb = *((const float2*)S.beta[c]);
            float4 a = A4[(c << 8) + tid];
            r[0].x -= a.x * bb.x; r[0].y -= a.y * bb.x; r[0].z -= a.z * bb.x; r[0].w -= a.w * bb.x;
            r[1].x -= a.x * bb.y; r[1].y -= a.y * bb.y; r[1].z -= a.z * bb.y; r[1].w -= a.w * bb.y;
        }
    };

    float4 r[2];
    matvec(r);
    #pragma unroll
    for (int t = 0; t < 2; ++t) ((float4*)S.rp[t])[tid] = r[t];
    __syncthreads();

    // per-wave exact medians -> initial scale (waves 0,1)
    if (wv_id < 2) {
        float fv[16]; unsigned kk[16];
        #pragma unroll
        for (int v = 0; v < 16; ++v) fv[v] = S.rp[wv_id][lane + (v << 6)];
        #pragma unroll
        for (int v = 0; v < 16; ++v) kk[v] = f2k(fv[v]);
        float med = wave_median(kk);
        #pragma unroll
        for (int v = 0; v < 16; ++v) kk[v] = f2k(fabsf(fv[v] - med));
        float mad = wave_median(kk);
        if (lane == 0) S.scale[wv_id] = 1.4815f * mad;
    }
    __syncthreads();

    float scale[2];
    #pragma unroll
    for (int t = 0; t < 2; ++t) scale[t] = S.scale[t];

    const float inv_denom = 1.0f / (2.0f * 0.7102f * (1024.0f - 32.0f - 1.0f));
    const float C2 = C_HUB * C_HUB;

    for (int it = 0; it < 3; ++it) {
        matvec(r);

        #pragma unroll
        for (int t = 0; t < 2; ++t) {
            float s = scale[t];
            float u0 = r[t].x / s, u1 = r[t].y / s, u2 = r[t].z / s, u3 = r[t].w / s;
            float part = 0.5f * (fminf(u0 * u0, C2) + fminf(u1 * u1, C2) +
                                 fminf(u2 * u2, C2) + fminf(u3 * u3, C2));
            float ps = wsum63(part);
            if (lane == 63) S.part[wv_id][t] = ps;
        }
        __syncthreads();

        #pragma unroll
        for (int t = 0; t < 2; ++t) {
            float ss = S.part[0][t] + S.part[1][t] + S.part[2][t] + S.part[3][t];
            float s = sqrtf(2.0f * scale[t] * scale[t] * inv_denom * ss);
            scale[t] = s;
            float4 rp;
            rp.x = fminf(fmaxf(r[t].x / s, -C_HUB), C_HUB) * s;
            rp.y = fminf(fmaxf(r[t].y / s, -C_HUB), C_HUB) * s;
            rp.z = fminf(fmaxf(r[t].z / s, -C_HUB), C_HUB) * s;
            rp.w = fminf(fmaxf(r[t].w / s, -C_HUB), C_HUB) * s;
            ((float4*)S.rp[t])[tid] = rp;
        }
        __syncthreads();

        // z[q][e] = sum_k A32[e][k] * rp[k+1-q]  (shifts applied to A via lanes)
        #pragma unroll 1
        for (int half = 0; half < 2; ++half) {
            float a0[4][2], a1[4][2], a2[4][2];
            #pragma unroll
            for (int cc = 0; cc < 4; ++cc)
                #pragma unroll
                for (int t = 0; t < 2; ++t) { a0[cc][t] = 0.f; a1[cc][t] = 0.f; a2[cc][t] = 0.f; }
            float wlast[4] = {0.f, 0.f, 0.f, 0.f};
            float rplast[2] = {0.f, 0.f};
            #pragma unroll 2
            for (int kk = 0; kk < 4; ++kk) {
                float4 rp4[2]; float rpl_new[2];
                #pragma unroll
                for (int t = 0; t < 2; ++t) {
                    rp4[t] = ((const float4*)S.rp[t])[(kk << 6) + lane];
                    rpl_new[t] = bcast63(rp4[t].w);
                }
                #pragma unroll
                for (int cc = 0; cc < 4; ++cc) {
                    const int cp = (wv_id << 3) + (half << 2) + cc;
                    float4 w4 = A4[(cp << 8) + (kk << 6) + lane];
                    float wprev = __shfl_up(w4.w, 1, 64);
                    if (lane == 0) wprev = wlast[cc];
                    float wnext = __shfl_down(w4.x, 1, 64);
                    if (lane == 63) wnext = 0.f;
                    float wcomp = (lane == 0) ? w4.x : 0.f;   // deferred chunk-edge term
                    #pragma unroll
                    for (int t = 0; t < 2; ++t) {
                        float4 rp = rp4[t];
                        a1[cc][t] += w4.x * rp.x + w4.y * rp.y + w4.z * rp.z + w4.w * rp.w;
                        a0[cc][t] += wprev * rp.x + w4.x * rp.y + w4.y * rp.z + w4.z * rp.w;
                        a2[cc][t] += w4.y * rp.x + w4.z * rp.y + w4.w * rp.z + wnext * rp.w
                                   + wcomp * rplast[t];
                    }
                    wlast[cc] = bcast63(w4.w);
                }
                #pragma unroll
                for (int t = 0; t < 2; ++t) rplast[t] = rpl_new[t];
            }
            #pragma unroll
            for (int cc = 0; cc < 4; ++cc) {
                const int cp = (wv_id << 3) + (half << 2) + cc;
                #pragma unroll
                for (int t = 0; t < 2; ++t) {
                    float z0 = wsum63(a0[cc][t]);
                    float z1 = wsum63(a1[cc][t]);
                    float z2 = wsum63(a2[cc][t]);
                    if (lane == 63) {
                        S.z[t][0][cp] = z0; S.z[t][1][cp] = z1; S.z[t][2][cp] = z2;
                    }
                }
            }
        }
        __syncthreads();

        // beta[c][t] += sum_e sum_q (sum_p kern[p][q] G[c+p-1][e]) z[q][e]
        if (tid < 64) {
            int t = tid >> 5, c = tid & 31;
            float kn[9];
            #pragma unroll
            for (int x = 0; x < 9; ++x) kn[x] = S.kern[t][x];
            float d = 0.f;
            #pragma unroll 4
            for (int e = 0; e < 32; ++e) {
                float gm = S.g[e][c];       // G[c-1][e]
                float gc = S.g[e][c + 1];   // G[c  ][e]
                float gp = S.g[e][c + 2];   // G[c+1][e]
                float z0 = S.z[t][0][e], z1 = S.z[t][1][e], z2 = S.z[t][2][e];
                d += (kn[0] * gm + kn[3] * gc + kn[6] * gp) * z0
                   + (kn[1] * gm + kn[4] * gc + kn[7] * gp) * z1
                   + (kn[2] * gm + kn[5] * gc + kn[8] * gp) * z2;
            }
            S.beta[c][t] += d;
        }
        __syncthreads();
    }

    if (tid < 64) {
        int t = tid >> 5, c = tid & 31, j = (b2 << 1) + t;
        float bv = S.beta[c][t];
        if (phase == 0) {
            vnew[(c << 10) + j] = bv;
            out[c * 2048 + 1024 + j] = bv;
        } else {
            out[c * 2048 + j] = bv;
        }
    }
}

// ---------------------------------------------------------------------------
// Mega kernel: whole DAG, 512 blocks, Gram parallelized (R8 lesson: single-
// block gram = ~130 us serial LDS-bound section while 511 blocks idle).
// ---------------------------------------------------------------------------
__global__ __launch_bounds__(256, 2) void mega_kernel(
    const float* __restrict__ X, const float* __restrict__ U,
    const float* __restrict__ V, const float* __restrict__ CK,
    float* __restrict__ out, float* __restrict__ XT, float* __restrict__ UT,
    float* __restrict__ Vn, float* __restrict__ Gpart, float* __restrict__ Ginv)
{
    __shared__ __align__(16) float sm[SM_FLOATS];
    cg::grid_group grid = cg::this_grid();
    const int b = blockIdx.x;

    // P0: transpose (all) + UT cols (64..95) + U-gram partials (32..63)
    transpose2(sm, X, XT, b);
    if (b >= 64 && b < 96) ut_col(U, UT, b - 64);
    if (b >= 32 && b < 64) gramU_partial(sm, U, Gpart, b - 32);
    grid.sync();

    // P1: reduce + invert (block 0)
    if (b == 0) reduce_inv(sm, Gpart, Ginv);
    grid.sync();

    // P2: IRLS phase 0
    irls2_block(sm, b, XT, UT, Ginv, CK, V, Vn, out, 0);
    grid.sync();

    // P3: Vn-gram partials (blocks 0..31)
    if (b < 32) gramVn_partial(sm, Vn, Gpart, b);
    grid.sync();

    // P4: reduce + invert (block 0)
    if (b == 0) reduce_inv(sm, Gpart, Ginv);
    grid.sync();

    // P5: IRLS phase 1
    irls2_block(sm, b, X, Vn, Ginv, CK + 1023 * 9, U, nullptr, out, 1);
}

// ---------------------------------------------------------------------------
// Fallback split kernels (used only if cooperative launch is rejected)
// ---------------------------------------------------------------------------
__global__ __launch_bounds__(256) void p0_kernel(
    const float* __restrict__ X, float* __restrict__ XT,
    const float* __restrict__ U, float* __restrict__ UT, float* __restrict__ Gpart) {
    __shared__ __align__(16) float sm[1056];
    const int b = blockIdx.x;
    transpose2(sm, X, XT, b);
    if (b >= 64 && b < 96) ut_col(U, UT, b - 64);
    if (b >= 32 && b < 64) gramU_partial(sm, U, Gpart, b - 32);
}
__global__ __launch_bounds__(256) void reduceinv_kernel(const float* __restrict__ Gpart,
                                                        float* __restrict__ Ginv) {
    __shared__ __align__(16) float sm[1056];
    reduce_inv(sm, Gpart, Ginv);
}
__global__ __launch_bounds__(256) void gramvn_kernel(const float* __restrict__ Vn,
                                                     float* __restrict__ Gpart) {
    __shared__ __align__(16) float sm[1056];
    gramVn_partial(sm, Vn, Gpart, blockIdx.x);
}
__global__ __launch_bounds__(256, 2) void irls2_kernel(
    const float* __restrict__ Yr, const float* __restrict__ A32,
    const float* __restrict__ Ginv, const float* __restrict__ kb,
    const float* __restrict__ bsrc, float* __restrict__ vnew,
    float* __restrict__ out, int phase) {
    __shared__ __align__(16) float sm[SM_FLOATS];
    irls2_block(sm, blockIdx.x, Yr, A32, Ginv, kb, bsrc, vnew, out, phase);
}

// ---------------------------------------------------------------------------
extern "C" void kernel_launch(void* const* d_in, const int* in_sizes, int n_in,
                              void* d_out, int out_size, void* d_ws, size_t ws_size,
                              hipStream_t stream) {
    const float* X  = (const float*)d_in[0];
    const float* U  = (const float*)d_in[1];
    const float* V  = (const float*)d_in[2];
    const float* CK = (const float*)d_in[3];
    float* out = (float*)d_out;

    float* f     = (float*)d_ws;
    float* XT    = f;                    // 1024*1024
    float* UT    = f + (1 << 20);        // 32*1024
    float* Vn    = UT + 32768;           // 32*1024
    float* Gpart = Vn + 32768;           // 32*1024
    float* Ginv  = Gpart + 32768;        // 1024

    void* args[] = {(void*)&X, (void*)&U, (void*)&V, (void*)&CK, (void*)&out,
                    (void*)&XT, (void*)&UT, (void*)&Vn, (void*)&Gpart, (void*)&Ginv};
    hipError_t err = hipLaunchCooperativeKernel((const void*)mega_kernel,
                                                dim3(512), dim3(256), args, 0, stream);
    if (err != hipSuccess) {
        (void)hipGetLastError();   // clear sticky error, take split path
        p0_kernel<<<512, 256, 0, stream>>>(X, XT, U, UT, Gpart);
        reduceinv_kernel<<<1, 256, 0, stream>>>(Gpart, Ginv);
        irls2_kernel<<<512, 256, 0, stream>>>(XT, UT, Ginv, CK, V, Vn, out, 0);
        gramvn_kernel<<<32, 256, 0, stream>>>(Vn, Gpart);
        reduceinv_kernel<<<1, 256, 0, stream>>>(Gpart, Ginv);
        irls2_kernel<<<512, 256, 0, stream>>>(X, Vn, Ginv, CK + 1023 * 9, U, nullptr, out, 1);
    }
}

// Round 10
// 307.817 us; speedup vs baseline: 1.6462x; 1.6462x over previous
//
#include <hip/hip_runtime.h>
#include <math.h>

#define C_HUB 1.345f

// ---------------- DPP helpers (VALU-pipe cross-lane) ----
template<int CTRL, bool BC>
__device__ __forceinline__ float fdpp(float old_, float src) {
    return __int_as_float(__builtin_amdgcn_update_dpp(
        __float_as_int(old_), __float_as_int(src), CTRL, 0xf, 0xf, BC));
}
// wave64 sum; result valid at lane 63 only
__device__ __forceinline__ float wsum63(float v) {
    v += fdpp<0x111, true>(0.f, v);   // row_shr:1
    v += fdpp<0x112, true>(0.f, v);   // row_shr:2
    v += fdpp<0x114, true>(0.f, v);   // row_shr:4
    v += fdpp<0x118, true>(0.f, v);   // row_shr:8
    v += fdpp<0x142, true>(0.f, v);   // row_bcast:15
    v += fdpp<0x143, true>(0.f, v);   // row_bcast:31
    return v;
}
template<int CTRL>
__device__ __forceinline__ unsigned udpp_keep(unsigned v) {
    return (unsigned)__builtin_amdgcn_update_dpp((int)v, (int)v, CTRL, 0xf, 0xf, false);
}
__device__ __forceinline__ unsigned wmin63(unsigned v) {
    v = min(v, udpp_keep<0x111>(v));
    v = min(v, udpp_keep<0x112>(v));
    v = min(v, udpp_keep<0x114>(v));
    v = min(v, udpp_keep<0x118>(v));
    v = min(v, udpp_keep<0x142>(v));
    v = min(v, udpp_keep<0x143>(v));
    return v;
}
__device__ __forceinline__ float bcast63(float v) {
    return __int_as_float(__builtin_amdgcn_readlane(__float_as_int(v), 63));
}

// monotone f32 <-> u32 key maps
__device__ __forceinline__ unsigned f2k(float f) {
    unsigned b = __float_as_uint(f);
    return (b & 0x80000000u) ? ~b : (b | 0x80000000u);
}
__device__ __forceinline__ float k2f(unsigned k) {
    return __uint_as_float((k & 0x80000000u) ? (k ^ 0x80000000u) : ~k);
}

// n-th smallest (1-indexed) of 1024 keys (16/lane), wave-synchronous
__device__ __forceinline__ unsigned wave_sel(const unsigned k[16], int n) {
    unsigned hi = 0u;
    for (int b = 31; b >= 0; --b) {
        unsigned pat = hi >> b;
        int cnt = 0;
        #pragma unroll
        for (int v = 0; v < 16; ++v)
            cnt += __popcll(__ballot((k[v] >> b) == pat));
        if (n > cnt) { hi |= (1u << b); n -= cnt; }
    }
    return hi;
}
// exact median (mean of middle two) of the 1024 keys
__device__ __forceinline__ float wave_median(const unsigned k[16]) {
    unsigned k1 = wave_sel(k, 512);
    int cle = 0;
    #pragma unroll
    for (int v = 0; v < 16; ++v) cle += __popcll(__ballot(k[v] <= k1));
    unsigned k2 = k1;
    if (cle < 513) {
        unsigned mg = 0xFFFFFFFFu;
        #pragma unroll
        for (int v = 0; v < 16; ++v) if (k[v] > k1) mg = min(mg, k[v]);
        mg = wmin63(mg);
        k2 = (unsigned)__builtin_amdgcn_readlane((int)mg, 63);
    }
    return 0.5f * (k2f(k1) + k2f(k2));
}

// ---------------- shared memory layout (single task) ----------------
struct Sm1 {
    float rp[1024];     // G staging first, then r_pseu
    float g[32][35];    // g[e][1+c] = Ginv[e][c]; cols 0,33 zero guards
    float z[3][32];
    float beta[32];
    float kern[9];
    float part[4];
    float scale[1];
};                      // 2286 floats -> ~9.2 KB; 4 blocks/CU = 37 KB

// ---------------------------------------------------------------------------
// P0: 1024 blocks. Block b transposes X-tile b; blocks 32..63 add U-Gram
// partials; 64..95 build UT columns; 96 zeroes Gacc (ws is 0xAA-poisoned).
// ---------------------------------------------------------------------------
__global__ __launch_bounds__(256) void p0_kernel(
    const float* __restrict__ X, float* __restrict__ XT,
    const float* __restrict__ U, float* __restrict__ UT,
    float* __restrict__ Gpart, float* __restrict__ Gacc)
{
    __shared__ float sm[32 * 33];
    const int b = blockIdx.x, tid = threadIdx.x;
    const int tx = tid & 31, ty = tid >> 5;
    const int bx = b & 31, by = b >> 5;

    for (int dy = ty; dy < 32; dy += 8)
        sm[dy * 33 + tx] = X[(by * 32 + dy) * 1024 + bx * 32 + tx];
    __syncthreads();
    for (int dy = ty; dy < 32; dy += 8)
        XT[(bx * 32 + dy) * 1024 + by * 32 + tx] = sm[tx * 33 + dy];

    if (b >= 32 && b < 64) {
        const int pb = b - 32;          // U rows 32pb..32pb+31
        __syncthreads();
        #pragma unroll
        for (int s = 0; s < 4; ++s) {
            int e = tid + (s << 8);
            int k = e >> 5, c = e & 31;
            sm[k * 33 + c] = U[((pb << 5) + k) * 32 + c];
        }
        __syncthreads();
        #pragma unroll
        for (int s = 0; s < 4; ++s) {
            int e = tid + (s << 8);
            int c1 = e >> 5, c2 = e & 31;
            float a = 0.f;
            #pragma unroll 8
            for (int k = 0; k < 32; ++k)
                a += sm[k * 33 + c1] * sm[k * 33 + c2];
            Gpart[(pb << 10) + e] = a;
        }
    } else if (b >= 64 && b < 96) {
        const int col = b - 64;
        for (int m = tid; m < 1024; m += 256)
            UT[(col << 10) + m] = U[m * 32 + col];
    } else if (b == 96) {
        #pragma unroll
        for (int s = 0; s < 4; ++s) Gacc[tid + (s << 8)] = 0.f;
    }
}

// ---------------------------------------------------------------------------
// IRLS, ONE task j = blockIdx.x, 256 threads, 1024 blocks, 4 blocks/CU.
// Per-block redundant Gram-sum + 1-wave register Gauss-Jordan (no inv kernel).
// Phase 0 ends with atomic outer-product into Gacc (= Vn Gram for phase 1).
// unroll 8 (matvec) / unroll 2 (z kk-loop) cap in-flight loads (R5 spill fix).
// ---------------------------------------------------------------------------
__global__ __launch_bounds__(256, 4) void irls1_kernel(
    const float* __restrict__ Yr, const float* __restrict__ A32,
    const float* __restrict__ Gsrc, int npart,
    const float* __restrict__ kb, const float* __restrict__ bsrc,
    float* __restrict__ vnew, float* __restrict__ Gacc,
    float* __restrict__ out, int phase)
{
    __shared__ __align__(16) Sm1 S;
    const int j = blockIdx.x;
    const int tid = threadIdx.x;
    const int lane = tid & 63, wv_id = tid >> 6;
    const float4* Y4 = (const float4*)Yr;
    const float4* A4 = (const float4*)A32;

    // ---- stage G (sum partials or load direct) into S.rp ----
    if (npart == 32) {
        for (int i = tid; i < 1024; i += 256) {
            float a = 0.f;
            #pragma unroll 8
            for (int p = 0; p < 32; ++p) a += Gsrc[(p << 10) + i];
            S.rp[i] = a;
        }
    } else {
        #pragma unroll
        for (int s = 0; s < 4; ++s) S.rp[tid + (s << 8)] = Gsrc[tid + (s << 8)];
    }
    __syncthreads();

    // ---- wave 0: register Gauss-Jordan -> S.g (guarded, transposed==symmetric)
    //      waves 1..3 concurrently stage beta/kern/guard columns ----
    if (wv_id == 0) {
        float col[32];
        if (lane < 32) {
            #pragma unroll
            for (int r = 0; r < 32; ++r) col[r] = S.rp[(r << 5) + lane];
        } else {
            #pragma unroll
            for (int r = 0; r < 32; ++r) col[r] = (lane - 32 == r) ? 1.f : 0.f;
        }
        #pragma unroll
        for (int k = 0; k < 32; ++k) {
            float piv = __shfl(col[k], k, 64);
            float pr = 1.0f / piv;
            col[k] *= pr;
            #pragma unroll
            for (int r = 0; r < 32; ++r) {
                if (r == k) continue;
                float f = __shfl(col[r], k, 64);
                col[r] -= f * col[k];
            }
        }
        if (lane >= 32) {
            int c = lane - 32;
            #pragma unroll
            for (int r = 0; r < 32; ++r) S.g[r][1 + c] = col[r];
        }
    } else if (tid >= 64 && tid < 96) {
        int c = tid - 64;
        S.beta[c] = (phase == 0) ? bsrc[(c << 10) + j] : bsrc[j * 32 + c];
    } else if (tid >= 96 && tid < 105) {
        int r = tid - 96;
        S.kern[r] = (phase == 0) ? kb[j * 9 + r] : kb[j * 9 + (r % 3) * 3 + (r / 3)];
    } else if (tid >= 128 && tid < 160) {
        S.g[tid - 128][0] = 0.f;
    } else if (tid >= 160 && tid < 192) {
        S.g[tid - 160][33] = 0.f;
    }
    __syncthreads();

    auto matvec = [&](float4& r) {
        r = Y4[(j << 8) + tid];
        #pragma unroll 8
        for (int c = 0; c < 32; ++c) {
            float b = S.beta[c];
            float4 a = A4[(c << 8) + tid];
            r.x -= a.x * b; r.y -= a.y * b; r.z -= a.z * b; r.w -= a.w * b;
        }
    };

    float4 r;
    matvec(r);
    ((float4*)S.rp)[tid] = r;
    __syncthreads();

    // ---- wave 0: exact medians -> initial scale ----
    if (wv_id == 0) {
        float fv[16]; unsigned kk[16];
        #pragma unroll
        for (int v = 0; v < 16; ++v) fv[v] = S.rp[lane + (v << 6)];
        #pragma unroll
        for (int v = 0; v < 16; ++v) kk[v] = f2k(fv[v]);
        float med = wave_median(kk);
        #pragma unroll
        for (int v = 0; v < 16; ++v) kk[v] = f2k(fabsf(fv[v] - med));
        float mad = wave_median(kk);
        if (lane == 0) S.scale[0] = 1.4815f * mad;
    }
    __syncthreads();

    float scale = S.scale[0];
    const float inv_denom = 1.0f / (2.0f * 0.7102f * (1024.0f - 32.0f - 1.0f));
    const float C2 = C_HUB * C_HUB;

    for (int it = 0; it < 3; ++it) {
        matvec(r);

        {
            float u0 = r.x / scale, u1 = r.y / scale, u2 = r.z / scale, u3 = r.w / scale;
            float part = 0.5f * (fminf(u0 * u0, C2) + fminf(u1 * u1, C2) +
                                 fminf(u2 * u2, C2) + fminf(u3 * u3, C2));
            float ps = wsum63(part);
            if (lane == 63) S.part[wv_id] = ps;
        }
        __syncthreads();

        {
            float ss = S.part[0] + S.part[1] + S.part[2] + S.part[3];
            scale = sqrtf(2.0f * scale * scale * inv_denom * ss);
            float4 rp;
            rp.x = fminf(fmaxf(r.x / scale, -C_HUB), C_HUB) * scale;
            rp.y = fminf(fmaxf(r.y / scale, -C_HUB), C_HUB) * scale;
            rp.z = fminf(fmaxf(r.z / scale, -C_HUB), C_HUB) * scale;
            rp.w = fminf(fmaxf(r.w / scale, -C_HUB), C_HUB) * scale;
            ((float4*)S.rp)[tid] = rp;
        }
        __syncthreads();

        // z[q][e] = sum_k A32[e][k] * rp[k+1-q]  (shifts applied to A via lanes)
        #pragma unroll 1
        for (int half = 0; half < 2; ++half) {
            float a0[4], a1[4], a2[4];
            #pragma unroll
            for (int cc = 0; cc < 4; ++cc) { a0[cc] = 0.f; a1[cc] = 0.f; a2[cc] = 0.f; }
            float wlast[4] = {0.f, 0.f, 0.f, 0.f};
            float rplast = 0.f;
            #pragma unroll 2
            for (int kk = 0; kk < 4; ++kk) {
                float4 rp4 = ((const float4*)S.rp)[(kk << 6) + lane];
                float rpl_new = bcast63(rp4.w);
                #pragma unroll
                for (int cc = 0; cc < 4; ++cc) {
                    const int cp = (wv_id << 3) + (half << 2) + cc;
                    float4 w4 = A4[(cp << 8) + (kk << 6) + lane];
                    float wprev = __shfl_up(w4.w, 1, 64);
                    if (lane == 0) wprev = wlast[cc];
                    float wnext = __shfl_down(w4.x, 1, 64);
                    if (lane == 63) wnext = 0.f;
                    float wcomp = (lane == 0) ? w4.x : 0.f;   // deferred chunk-edge term
                    a1[cc] += w4.x * rp4.x + w4.y * rp4.y + w4.z * rp4.z + w4.w * rp4.w;
                    a0[cc] += wprev * rp4.x + w4.x * rp4.y + w4.y * rp4.z + w4.z * rp4.w;
                    a2[cc] += w4.y * rp4.x + w4.z * rp4.y + w4.w * rp4.z + wnext * rp4.w
                            + wcomp * rplast;
                    wlast[cc] = bcast63(w4.w);
                }
                rplast = rpl_new;
            }
            #pragma unroll
            for (int cc = 0; cc < 4; ++cc) {
                const int cp = (wv_id << 3) + (half << 2) + cc;
                float z0 = wsum63(a0[cc]);
                float z1 = wsum63(a1[cc]);
                float z2 = wsum63(a2[cc]);
                if (lane == 63) {
                    S.z[0][cp] = z0; S.z[1][cp] = z1; S.z[2][cp] = z2;
                }
            }
        }
        __syncthreads();

        // beta[c] += sum_e sum_q (sum_p kern[p][q] G[c+p-1][e]) z[q][e]
        if (tid < 32) {
            int c = tid;
            float kn[9];
            #pragma unroll
            for (int x = 0; x < 9; ++x) kn[x] = S.kern[x];
            float d = 0.f;
            #pragma unroll 4
            for (int e = 0; e < 32; ++e) {
                float gm = S.g[e][c];       // G[c-1][e]
                float gc = S.g[e][c + 1];   // G[c  ][e]
                float gp = S.g[e][c + 2];   // G[c+1][e]
                float z0 = S.z[0][e], z1 = S.z[1][e], z2 = S.z[2][e];
                d += (kn[0] * gm + kn[3] * gc + kn[6] * gp) * z0
                   + (kn[1] * gm + kn[4] * gc + kn[7] * gp) * z1
                   + (kn[2] * gm + kn[5] * gc + kn[8] * gp) * z2;
            }
            S.beta[c] += d;
        }
        __syncthreads();
    }

    if (tid < 32) {
        int c = tid;
        float bv = S.beta[c];
        if (phase == 0) {
            vnew[(c << 10) + j] = bv;
            out[c * 2048 + 1024 + j] = bv;
        } else {
            out[c * 2048 + j] = bv;
        }
    }
    if (phase == 0) {
        // Gacc += beta betaT  (phase-1 Gram, atomically accumulated)
        #pragma unroll
        for (int s = 0; s < 4; ++s) {
            int e = (tid << 2) + s;
            atomicAdd(&Gacc[e], S.beta[e >> 5] * S.beta[e & 31]);
        }
    }
}

// ---------------------------------------------------------------------------
extern "C" void kernel_launch(void* const* d_in, const int* in_sizes, int n_in,
                              void* d_out, int out_size, void* d_ws, size_t ws_size,
                              hipStream_t stream) {
    const float* X  = (const float*)d_in[0];
    const float* U  = (const float*)d_in[1];
    const float* V  = (const float*)d_in[2];
    const float* CK = (const float*)d_in[3];
    float* out = (float*)d_out;

    float* f     = (float*)d_ws;
    float* XT    = f;                    // 1024*1024
    float* UT    = f + (1 << 20);        // 32*1024
    float* Vn    = UT + 32768;           // 32*1024
    float* Gpart = Vn + 32768;           // 32*1024
    float* Gacc  = Gpart + 32768;        // 1024

    p0_kernel<<<1024, 256, 0, stream>>>(X, XT, U, UT, Gpart, Gacc);
    irls1_kernel<<<1024, 256, 0, stream>>>(XT, UT, Gpart, 32, CK, V, Vn, Gacc, out, 0);
    irls1_kernel<<<1024, 256, 0, stream>>>(X, Vn, Gacc, 0, CK + 1023 * 9, U, nullptr, nullptr, out, 1);
}